// Round 15
// baseline (841.872 us; speedup 1.0000x reference)
//
#include <hip/hip_runtime.h>
#include <math.h>

#define N_ 8192
#define H_ 128
#define E_ 262144
#define K_ 16
#define SLABJ 1024
#define CHUNKJ 512

typedef __attribute__((ext_vector_type(8))) short bshort8;
typedef __attribute__((ext_vector_type(16))) float f32x16;
typedef unsigned long long u64;

// ---------------- degree / normalization ----------------
__global__ void k_deg_init(float* deg) {
  int i = blockIdx.x * 256 + threadIdx.x;
  deg[i] = 1.0f;
}

__global__ void k_deg_scatter(const int* __restrict__ ei, const float* __restrict__ ew,
                              float* deg) {
  int e = blockIdx.x * 256 + threadIdx.x;
  atomicAdd(&deg[ei[E_ + e]], ew[e]);
}

__global__ void k_dis(float* deg) {
  int i = blockIdx.x * 256 + threadIdx.x;
  deg[i] = rsqrtf(deg[i]);
}

// ---------------- one-time CSR build ----------------
__global__ void k_hist(const int* __restrict__ ei, int* hist) {
  int e = blockIdx.x * 256 + threadIdx.x;
  atomicAdd(&hist[ei[E_ + e]], 1);
}

__global__ void k_scan(int* hist, int* rowptr) {
  __shared__ int part[256];
  __shared__ int partx[257];
  int t = threadIdx.x;
  int base = t * 32;
  int loc[32];
  int s = 0;
#pragma unroll
  for (int i = 0; i < 32; ++i) { loc[i] = s; s += hist[base + i]; }
  part[t] = s;
  __syncthreads();
  if (t == 0) {
    int r = 0;
    for (int i = 0; i < 256; ++i) { partx[i] = r; r += part[i]; }
    partx[256] = r;
  }
  __syncthreads();
  int b = partx[t];
#pragma unroll
  for (int i = 0; i < 32; ++i) {
    rowptr[base + i] = b + loc[i];
    hist[base + i] = b + loc[i];
  }
  if (t == 0) rowptr[N_] = partx[256];
}

__global__ void k_edgebuild(const int* __restrict__ ei, const float* __restrict__ ew,
                            const float* __restrict__ dis, int* cursor,
                            int* __restrict__ srcS, float* __restrict__ normS) {
  int e = blockIdx.x * 256 + threadIdx.x;
  int s = ei[e], d = ei[E_ + e];
  int pos = atomicAdd(&cursor[d], 1);
  srcS[pos] = s;
  normS[pos] = dis[s] * ew[e] * dis[d];
}

// ---------------- bf16 helpers ----------------
__device__ __forceinline__ unsigned short f2bf_rne(float x) {
  unsigned u = __builtin_bit_cast(unsigned, x);
  unsigned r = ((u >> 16) & 1u) + 0x7fffu;
  return (unsigned short)((u + r) >> 16);
}
__device__ __forceinline__ float bf2f(unsigned short b) {
  unsigned u = ((unsigned)b) << 16;
  return __builtin_bit_cast(float, u);
}

// ---------------- one-shot weight frag prep (all 3 layers) ----------------
struct WP { const float* p[12]; };  // per layer: wg, ew1, ew2, ew3

__global__ void k_wprepAll(WP wp, bshort8* __restrict__ wAll) {
  int id = blockIdx.x * 256 + threadIdx.x;  // 21504
  int layer = id / 7168;
  int r = id - layer * 7168;
  bshort8* base = wAll + layer * 14336;
  const float* src;
  bshort8 *dH, *dL;
  int slot, kind;
  if (r < 2048)      { kind = 0; slot = r;        src = wp.p[layer*4+0]; dH = base;         dL = base + 2048; }
  else if (r < 4096) { kind = 1; slot = r - 2048; src = wp.p[layer*4+1]; dH = base + 4096;  dL = base + 6144; }
  else if (r < 5120) { kind = 2; slot = r - 4096; src = wp.p[layer*4+2]; dH = base + 8192;  dL = base + 9216; }
  else               { kind = 3; slot = r - 5120; src = wp.p[layer*4+3]; dH = base + 10240; dL = base + 12288; }
  int lane = slot & 63;
  int n, k0;
  if (kind == 2) {
    int ks = (slot >> 6) & 3, nt = slot >> 8;
    n = nt * 32 + (lane & 31);
    k0 = ks * 16 + (lane >> 5) * 8;
  } else {
    int ks = (slot >> 6) & 7, nt = slot >> 9;
    n = nt * 32 + (lane & 31);
    k0 = ks * 16 + (lane >> 5) * 8;
  }
  bshort8 h, l;
#pragma unroll
  for (int i = 0; i < 8; ++i) {
    int k = k0 + i;
    float v;
    if (kind == 1) v = (n < 64) ? (src[k * 64 + n] - src[(128 + k) * 64 + n])
                                : src[(128 + k) * 64 + (n - 64)];
    else v = src[k * 128 + n];
    unsigned short hb = f2bf_rne(v);
    h[i] = (short)hb;
    l[i] = (short)f2bf_rne(v - bf2f(hb));
  }
  dH[slot] = h;
  dL[slot] = l;
}

// ---------------- MFMA GEMM: [8192x128] @ [128x128], fp32 A (staged) ----------------
__global__ __launch_bounds__(256, 3) void k_gemmM(const float* __restrict__ A,
                                                  const bshort8* __restrict__ wfH,
                                                  const bshort8* __restrict__ wfL,
                                                  float* __restrict__ C) {
  __shared__ short aHs[32 * 132], aLs[32 * 132];
  int t = threadIdx.x;
  int r0 = blockIdx.x * 32;
  int w = t >> 6, lane = t & 63, q = lane & 31, half = lane >> 5;

  {
    int r = t >> 3;
    int kc = (t & 7) * 16;
    const float* p = A + (r0 + r) * 128 + kc;
#pragma unroll
    for (int e4 = 0; e4 < 4; ++e4) {
      float4 v = *(const float4*)(p + e4 * 4);
      float vals[4] = {v.x, v.y, v.z, v.w};
      unsigned short hs[4], ls[4];
#pragma unroll
      for (int i = 0; i < 4; ++i) {
        hs[i] = f2bf_rne(vals[i]);
        ls[i] = f2bf_rne(vals[i] - bf2f(hs[i]));
      }
      int off = r * 132 + kc + e4 * 4;
      *(u64*)&aHs[off] = ((u64)hs[0]) | ((u64)hs[1] << 16) | ((u64)hs[2] << 32) | ((u64)hs[3] << 48);
      *(u64*)&aLs[off] = ((u64)ls[0]) | ((u64)ls[1] << 16) | ((u64)ls[2] << 32) | ((u64)ls[3] << 48);
    }
  }
  bshort8 bH[8], bL[8];
#pragma unroll
  for (int ks = 0; ks < 8; ++ks) {
    bH[ks] = wfH[(w * 8 + ks) * 64 + lane];
    bL[ks] = wfL[(w * 8 + ks) * 64 + lane];
  }
  __syncthreads();

  f32x16 accP, accQ;
#pragma unroll
  for (int r = 0; r < 16; ++r) { accP[r] = 0.f; accQ[r] = 0.f; }
#pragma unroll
  for (int ks = 0; ks < 8; ++ks) {
    int off = q * 132 + ks * 16 + half * 8;
    union { bshort8 v; u64 u[2]; } aH, aL;
    aH.u[0] = *(const u64*)&aHs[off];
    aH.u[1] = *(const u64*)&aHs[off + 4];
    aL.u[0] = *(const u64*)&aLs[off];
    aL.u[1] = *(const u64*)&aLs[off + 4];
    accQ = __builtin_amdgcn_mfma_f32_32x32x16_bf16(aL.v, bH[ks], accQ, 0, 0, 0);
    accQ = __builtin_amdgcn_mfma_f32_32x32x16_bf16(aH.v, bL[ks], accQ, 0, 0, 0);
    accP = __builtin_amdgcn_mfma_f32_32x32x16_bf16(aH.v, bH[ks], accP, 0, 0, 0);
  }
#pragma unroll
  for (int reg = 0; reg < 16; ++reg) {
    int row = (reg & 3) + 8 * (reg >> 2) + 4 * half;
    C[(r0 + row) * 128 + w * 32 + q] = accP[reg] + accQ[reg];
  }
}

// ---------------- MFMA GEMM, frag-A input (no staging) ----------------
__global__ void k_gemmMF(const bshort8* __restrict__ fAH, const bshort8* __restrict__ fAL,
                         const bshort8* __restrict__ wfH, const bshort8* __restrict__ wfL,
                         float* __restrict__ C) {
  int t = threadIdx.x;
  int rt = blockIdx.x >> 1;
  int w = (blockIdx.x & 1) * 2 + (t >> 6);
  int lane = t & 63, q = lane & 31, half = lane >> 5;

  bshort8 bH[8], bL[8], aH[8], aL[8];
#pragma unroll
  for (int ks = 0; ks < 8; ++ks) {
    bH[ks] = wfH[(w * 8 + ks) * 64 + lane];
    bL[ks] = wfL[(w * 8 + ks) * 64 + lane];
    aH[ks] = fAH[(rt * 8 + ks) * 64 + lane];
    aL[ks] = fAL[(rt * 8 + ks) * 64 + lane];
  }
  f32x16 accP, accQ;
#pragma unroll
  for (int r = 0; r < 16; ++r) { accP[r] = 0.f; accQ[r] = 0.f; }
#pragma unroll
  for (int ks = 0; ks < 8; ++ks) {
    accQ = __builtin_amdgcn_mfma_f32_32x32x16_bf16(aL[ks], bH[ks], accQ, 0, 0, 0);
    accQ = __builtin_amdgcn_mfma_f32_32x32x16_bf16(aH[ks], bL[ks], accQ, 0, 0, 0);
    accP = __builtin_amdgcn_mfma_f32_32x32x16_bf16(aH[ks], bH[ks], accP, 0, 0, 0);
  }
#pragma unroll
  for (int reg = 0; reg < 16; ++reg) {
    int row = (reg & 3) + 8 * (reg >> 2) + 4 * half;
    C[(rt * 32 + row) * 128 + w * 32 + q] = accP[reg] + accQ[reg];
  }
}

// ---------------- fused GCN aggregation (CSR gather) ----------------
__global__ __launch_bounds__(256) void k_gcn_agg(const float* __restrict__ h,
                                                 const float* __restrict__ dis,
                                                 const int* __restrict__ rowptr,
                                                 const int* __restrict__ srcS,
                                                 const float* __restrict__ normS,
                                                 const float* __restrict__ bg,
                                                 float* __restrict__ n_out,
                                                 float* __restrict__ sn) {
  __shared__ float part[4];
  int t = threadIdx.x;
  int i = blockIdx.x * 2 + (t >> 7);
  int c = t & 127;
  float di = dis[i];
  float a0 = di * di * h[i * 128 + c], a1 = 0.f, a2 = 0.f, a3 = 0.f;
  int e0 = rowptr[i], e1 = rowptr[i + 1];
  int e = e0;
  for (; e + 4 <= e1; e += 4) {
    int s0 = srcS[e], s1 = srcS[e + 1], s2 = srcS[e + 2], s3 = srcS[e + 3];
    float w0 = normS[e], w1 = normS[e + 1], w2 = normS[e + 2], w3 = normS[e + 3];
    a0 += w0 * h[s0 * 128 + c];
    a1 += w1 * h[s1 * 128 + c];
    a2 += w2 * h[s2 * 128 + c];
    a3 += w3 * h[s3 * 128 + c];
  }
  for (; e < e1; ++e) a0 += normS[e] * h[srcS[e] * 128 + c];
  float v = tanhf(a0 + a1 + a2 + a3 + bg[c]);
  n_out[i * 128 + c] = v;
  float vv = v * v;
#pragma unroll
  for (int off = 32; off; off >>= 1) vv += __shfl_down(vv, off, 64);
  if ((t & 63) == 0) part[t >> 6] = vv;
  __syncthreads();
  if ((t & 127) == 0) sn[i] = part[t >> 6] + part[(t >> 6) + 1];
}

// ---------------- feature frag prep ----------------
__global__ void k_fragprep(const float* __restrict__ src, bshort8* __restrict__ hiA,
                           bshort8* __restrict__ loA) {
  int t = blockIdx.x * 256 + threadIdx.x;
  int j = t >> 4, slot = t & 15;
  const float* p = src + j * 128 + slot * 8;
  float4 f0 = *(const float4*)p;
  float4 f1 = *(const float4*)(p + 4);
  float f[8] = {f0.x, f0.y, f0.z, f0.w, f1.x, f1.y, f1.z, f1.w};
  bshort8 h, l;
#pragma unroll
  for (int i = 0; i < 8; ++i) {
    unsigned short hb = f2bf_rne(f[i]);
    h[i] = (short)hb;
    l[i] = (short)f2bf_rne(f[i] - bf2f(hb));
  }
  int ks = slot >> 1, half = slot & 1;
  int dst = ((j >> 5) * 8 + ks) * 64 + half * 32 + (j & 31);
  hiA[dst] = h;
  loA[dst] = l;
}

// ---------------- packed-key helpers ----------------
__device__ __forceinline__ u64 packkey(float d, int j) {
  unsigned m = __builtin_bit_cast(unsigned, d);
  m = (m & 0x80000000u) ? ~m : (m | 0x80000000u);
  return (((u64)m) << 32) | (unsigned)j;
}

__device__ __forceinline__ float unpackd(u64 key) {
  unsigned m = (unsigned)(key >> 32);
  unsigned u = (m & 0x80000000u) ? (m & 0x7fffffffu) : ~m;
  return __builtin_bit_cast(float, u);
}

__device__ __forceinline__ void ins4(u64* tk, u64 x) {
  bool c[4];
#pragma unroll
  for (int s = 0; s < 4; ++s) c[s] = x < tk[s];
#pragma unroll
  for (int s = 3; s >= 1; --s) tk[s] = c[s - 1] ? tk[s - 1] : (c[s] ? x : tk[s]);
  tk[0] = c[0] ? x : tk[0];
}

__device__ __forceinline__ void ins16(u64* tk, u64 x) {
  bool c[16];
#pragma unroll
  for (int s = 0; s < 16; ++s) c[s] = x < tk[s];
#pragma unroll
  for (int s = 15; s >= 1; --s) tk[s] = c[s - 1] ? tk[s - 1] : (c[s] ? x : tk[s]);
  tk[0] = c[0] ? x : tk[0];
}

// ---------------- phase A (tau bound only): 4 chunks x 512 j, per-lane sorted-4 ----------------
__global__ __launch_bounds__(256, 2) void k_knnA(const bshort8* __restrict__ fragHi,
                                                 const bshort8* __restrict__ fragLo,
                                                 const float* __restrict__ sn,
                                                 u64* __restrict__ candR) {
  __shared__ float snS[CHUNKJ];
  int t = threadIdx.x;
  int qtile = blockIdx.x, chunk = blockIdx.y;
  int wave = t >> 6, lane = t & 63;
  int q = lane & 31, half = lane >> 5;

  snS[t] = sn[chunk * CHUNKJ + t];
  snS[t + 256] = sn[chunk * CHUNKJ + t + 256];

  bshort8 bHi[8], bLo[8];
#pragma unroll
  for (int ks = 0; ks < 8; ++ks) {
    int o = (qtile * 8 + ks) * 64 + lane;
    bHi[ks] = fragHi[o];
    bLo[ks] = fragLo[o];
  }
  __syncthreads();

  u64 tk[4];
#pragma unroll
  for (int s = 0; s < 4; ++s) tk[s] = ~0ULL;

  int jt0 = chunk * 16 + wave * 4;
  bshort8 pH[4], pL[4];
#pragma unroll
  for (int k4 = 0; k4 < 4; ++k4) {
    int o = (jt0 * 8 + k4) * 64 + lane;
    pH[k4] = fragHi[o];
    pL[k4] = fragLo[o];
  }

  for (int ti = 0; ti < 4; ++ti) {
    int jt = jt0 + ti;
    f32x16 accP, accQ;
#pragma unroll
    for (int r = 0; r < 16; ++r) { accP[r] = 0.f; accQ[r] = 0.f; }

    bshort8 qH[4], qL[4];
#pragma unroll
    for (int k4 = 0; k4 < 4; ++k4) {
      int o = (jt * 8 + 4 + k4) * 64 + lane;
      qH[k4] = fragHi[o];
      qL[k4] = fragLo[o];
    }
#pragma unroll
    for (int k4 = 0; k4 < 4; ++k4) {
      accQ = __builtin_amdgcn_mfma_f32_32x32x16_bf16(pL[k4], bHi[k4], accQ, 0, 0, 0);
      accQ = __builtin_amdgcn_mfma_f32_32x32x16_bf16(pH[k4], bLo[k4], accQ, 0, 0, 0);
      accP = __builtin_amdgcn_mfma_f32_32x32x16_bf16(pH[k4], bHi[k4], accP, 0, 0, 0);
    }
    if (ti < 3) {
#pragma unroll
      for (int k4 = 0; k4 < 4; ++k4) {
        int o = ((jt + 1) * 8 + k4) * 64 + lane;
        pH[k4] = fragHi[o];
        pL[k4] = fragLo[o];
      }
    }
#pragma unroll
    for (int k4 = 0; k4 < 4; ++k4) {
      accQ = __builtin_amdgcn_mfma_f32_32x32x16_bf16(qL[k4], bHi[4 + k4], accQ, 0, 0, 0);
      accQ = __builtin_amdgcn_mfma_f32_32x32x16_bf16(qH[k4], bLo[4 + k4], accQ, 0, 0, 0);
      accP = __builtin_amdgcn_mfma_f32_32x32x16_bf16(qH[k4], bHi[4 + k4], accP, 0, 0, 0);
    }

    int jbase = (wave * 4 + ti) * 32;
#pragma unroll
    for (int rp = 0; rp < 8; ++rp) {
      int r0 = rp * 2;
      int row0 = (r0 & 3) + 8 * (r0 >> 2) + 4 * half;
      float d0 = snS[jbase + row0] - 2.0f * (accP[r0] + accQ[r0]);
      float d1 = snS[jbase + row0 + 1] - 2.0f * (accP[r0 + 1] + accQ[r0 + 1]);
      u64 k0 = packkey(d0, chunk * CHUNKJ + jbase + row0);
      u64 k1 = packkey(d1, chunk * CHUNKJ + jbase + row0 + 1);
      u64 km = k0 < k1 ? k0 : k1;
      if (km < tk[3]) {
        if (k0 < tk[3]) ins4(tk, k0);
        if (k1 < tk[3]) ins4(tk, k1);
      }
    }
  }

  int g = wave * 2 + half;
#pragma unroll
  for (int s = 0; s < 4; ++s)
    candR[(size_t)(chunk * 32 + g * 4 + s) * N_ + qtile * 32 + q] = tk[s];
}

// tau = 16th smallest of 32 sorted-4 lists (upper bound; truncation only loosens)
__global__ __launch_bounds__(256) void k_tauseedX(const u64* __restrict__ candR,
                                                  int* __restrict__ cursor,
                                                  float* __restrict__ tauD) {
  __shared__ u64 mb[64 * 65];
  int t = threadIdx.x;
  int ql = t >> 2, j = t & 3;
  int q = blockIdx.x * 64 + ql;

  int rb[8];
#pragma unroll
  for (int k = 0; k < 8; ++k) {
    int L = 8 * j + k;
    rb[k] = (L >> 3) * 32 + (L & 7) * 4;
  }
  int h0 = 0, h1 = 0, h2 = 0, h3 = 0, h4 = 0, h5 = 0, h6 = 0, h7 = 0;
  for (int step = 0; step < 16; ++step) {
    u64 best = (h0 < 4) ? candR[(size_t)(rb[0] + h0) * N_ + q] : ~0ULL;
    int bg = 0;
    u64 b;
    b = (h1 < 4) ? candR[(size_t)(rb[1] + h1) * N_ + q] : ~0ULL; if (b < best) { best = b; bg = 1; }
    b = (h2 < 4) ? candR[(size_t)(rb[2] + h2) * N_ + q] : ~0ULL; if (b < best) { best = b; bg = 2; }
    b = (h3 < 4) ? candR[(size_t)(rb[3] + h3) * N_ + q] : ~0ULL; if (b < best) { best = b; bg = 3; }
    b = (h4 < 4) ? candR[(size_t)(rb[4] + h4) * N_ + q] : ~0ULL; if (b < best) { best = b; bg = 4; }
    b = (h5 < 4) ? candR[(size_t)(rb[5] + h5) * N_ + q] : ~0ULL; if (b < best) { best = b; bg = 5; }
    b = (h6 < 4) ? candR[(size_t)(rb[6] + h6) * N_ + q] : ~0ULL; if (b < best) { best = b; bg = 6; }
    b = (h7 < 4) ? candR[(size_t)(rb[7] + h7) * N_ + q] : ~0ULL; if (b < best) { best = b; bg = 7; }
    mb[ql * 65 + j * 16 + step] = best;
    h0 += (bg == 0); h1 += (bg == 1); h2 += (bg == 2); h3 += (bg == 3);
    h4 += (bg == 4); h5 += (bg == 5); h6 += (bg == 6); h7 += (bg == 7);
  }
  __syncthreads();
  if (t < 64) {
    int qq = blockIdx.x * 64 + t;
    int base = t * 65;
    int g0 = 0, g1 = 0, g2 = 0, g3 = 0;
    u64 best = 0;
    for (int step = 0; step < 16; ++step) {
      best = mb[base + g0];
      int bg = 0;
      u64 b;
      b = mb[base + 16 + g1]; if (b < best) { best = b; bg = 1; }
      b = mb[base + 32 + g2]; if (b < best) { best = b; bg = 2; }
      b = mb[base + 48 + g3]; if (b < best) { best = b; bg = 3; }
      g0 += (bg == 0); g1 += (bg == 1); g2 += (bg == 2); g3 += (bg == 3);
    }
    tauD[qq] = unpackd(best);
    cursor[qq] = 0;
  }
}

// ---------------- phase B: LDS-shared A-tiles, 4 qtiles/block, all 8 slabs ----------------
// block = 4 waves; wave w owns qtile blockIdx.x*4+w. A-tiles double-buffered in LDS.
__global__ __launch_bounds__(256, 2) void k_knnB(const bshort8* __restrict__ fragHi,
                                                 const bshort8* __restrict__ fragLo,
                                                 const float* __restrict__ sn,
                                                 const float* __restrict__ tauD,
                                                 int* __restrict__ cursor,
                                                 u64* __restrict__ accept,
                                                 u64* __restrict__ accExt) {
  __shared__ float snS[SLABJ];          // 4 KB
  __shared__ bshort8 tH[2][512];        // 16 KB
  __shared__ bshort8 tL[2][512];        // 16 KB
  int t = threadIdx.x;
  int qg4 = blockIdx.x, slab = blockIdx.y;
  int wave = t >> 6, lane = t & 63;
  int q = lane & 31, half = lane >> 5;
  int qtile = qg4 * 4 + wave;
  int qgl = qtile * 32 + q;

#pragma unroll
  for (int p = 0; p < 4; ++p) snS[t + 256 * p] = sn[slab * SLABJ + t + 256 * p];

  bshort8 bHi[8], bLo[8];
#pragma unroll
  for (int ks = 0; ks < 8; ++ks) {
    int o = (qtile * 8 + ks) * 64 + lane;
    bHi[ks] = fragHi[o];
    bLo[ks] = fragLo[o];
  }
  float tD = tauD[qgl];

  // stage tile 0
  {
    size_t src = (size_t)(slab * 32) * 512;
    tH[0][t] = fragHi[src + t];
    tH[0][t + 256] = fragHi[src + t + 256];
    tL[0][t] = fragLo[src + t];
    tL[0][t + 256] = fragLo[src + t + 256];
  }
  __syncthreads();

  u64 buf[8];
  int cnt = 0;

  for (int ti = 0; ti < 32; ++ti) {
    int cb = ti & 1;
    // stage next tile into the other buffer
    if (ti < 31) {
      size_t src = (size_t)(slab * 32 + ti + 1) * 512;
      int nb = cb ^ 1;
      tH[nb][t] = fragHi[src + t];
      tH[nb][t + 256] = fragHi[src + t + 256];
      tL[nb][t] = fragLo[src + t];
      tL[nb][t + 256] = fragLo[src + t + 256];
    }

    f32x16 accP, accQ;
#pragma unroll
    for (int r = 0; r < 16; ++r) { accP[r] = 0.f; accQ[r] = 0.f; }
#pragma unroll
    for (int ks = 0; ks < 8; ++ks) {
      bshort8 aH = tH[cb][ks * 64 + lane];
      bshort8 aL = tL[cb][ks * 64 + lane];
      accQ = __builtin_amdgcn_mfma_f32_32x32x16_bf16(aL, bHi[ks], accQ, 0, 0, 0);
      accQ = __builtin_amdgcn_mfma_f32_32x32x16_bf16(aH, bLo[ks], accQ, 0, 0, 0);
      accP = __builtin_amdgcn_mfma_f32_32x32x16_bf16(aH, bHi[ks], accP, 0, 0, 0);
    }

    int jbase = ti * 32;
#pragma unroll
    for (int rp = 0; rp < 8; ++rp) {
      int r0 = rp * 2;
      int row0 = (r0 & 3) + 8 * (r0 >> 2) + 4 * half;
      float d0 = snS[jbase + row0] - 2.0f * (accP[r0] + accQ[r0]);
      float d1 = snS[jbase + row0 + 1] - 2.0f * (accP[r0 + 1] + accQ[r0 + 1]);
      if (d0 <= tD) {
        u64 k0 = packkey(d0, slab * SLABJ + jbase + row0);
        if (cnt < 8) {
#pragma unroll
          for (int s = 0; s < 8; ++s)
            if (s == cnt) buf[s] = k0;
          ++cnt;
        } else {
          int pos = atomicAdd(&cursor[qgl], 1);
          if (pos < 128) accept[(size_t)pos * N_ + qgl] = k0;
          else if (pos < 192) accExt[(size_t)(pos - 128) * N_ + qgl] = k0;
        }
      }
      if (d1 <= tD) {
        u64 k1 = packkey(d1, slab * SLABJ + jbase + row0 + 1);
        if (cnt < 8) {
#pragma unroll
          for (int s = 0; s < 8; ++s)
            if (s == cnt) buf[s] = k1;
          ++cnt;
        } else {
          int pos = atomicAdd(&cursor[qgl], 1);
          if (pos < 128) accept[(size_t)pos * N_ + qgl] = k1;
          else if (pos < 192) accExt[(size_t)(pos - 128) * N_ + qgl] = k1;
        }
      }
    }
    __syncthreads();
  }

  if (cnt > 0) {
    int pos = atomicAdd(&cursor[qgl], cnt);
#pragma unroll
    for (int s = 0; s < 8; ++s) {
      if (s < cnt) {
        int slot = pos + s;
        if (slot < 128) accept[(size_t)slot * N_ + qgl] = buf[s];
        else if (slot < 192) accExt[(size_t)(slot - 128) * N_ + qgl] = buf[s];
      }
    }
  }
}

// ---------------- phase C: wave-parallel exact top-16 (4 lanes/query) ----------------
__global__ __launch_bounds__(256) void k_select(const u64* __restrict__ accept,
                                                const u64* __restrict__ accExt,
                                                const int* __restrict__ cursor,
                                                int* __restrict__ idxo) {
  __shared__ u64 mb[64 * 65];
  int t = threadIdx.x;
  int ql = t >> 2;
  int j = t & 3;
  int q = blockIdx.x * 64 + ql;
  int c = cursor[q];
  if (c > 192) c = 192;
  u64 tk[16];
#pragma unroll
  for (int s = 0; s < 16; ++s) tk[s] = ~0ULL;
  for (int i = j; i < c; i += 4) {
    u64 x = (i < 128) ? accept[(size_t)i * N_ + q] : accExt[(size_t)(i - 128) * N_ + q];
    if (x < tk[15]) ins16(tk, x);
  }
#pragma unroll
  for (int s = 0; s < 16; ++s) mb[ql * 65 + j * 16 + s] = tk[s];
  __syncthreads();
  if (t < 64) {
    int qq = blockIdx.x * 64 + t;
    int base = t * 65;
    int h0 = 0, h1 = 0, h2 = 0, h3 = 0;
    for (int step = 0; step < 16; ++step) {
      u64 best = mb[base + h0];
      int bg = 0;
      u64 b;
      b = mb[base + 16 + h1]; if (b < best) { best = b; bg = 1; }
      b = mb[base + 32 + h2]; if (b < best) { best = b; bg = 2; }
      b = mb[base + 48 + h3]; if (b < best) { best = b; bg = 3; }
      idxo[qq * 16 + step] = (int)(unsigned)(best & 0xffffffffULL);
      h0 += (bg == 0); h1 += (bg == 1); h2 += (bg == 2); h3 += (bg == 3);
    }
  }
}

// ---------------- MFMA EdgeConv MLP ----------------
__global__ __launch_bounds__(256, 3) void k_mlpM(
    const float* __restrict__ ab, const int* __restrict__ idx,
    const bshort8* __restrict__ w2fH, const bshort8* __restrict__ w2fL,
    const bshort8* __restrict__ w3fH, const bshort8* __restrict__ w3fL,
    const float* __restrict__ b1g, const float* __restrict__ b2g,
    const float* __restrict__ b3g, const float* __restrict__ nadd,
    float* __restrict__ eout) {
  __shared__ short h1H[64 * 68], h1L[64 * 68];
  __shared__ short h2H[64 * 132], h2L[64 * 132];
  int t = threadIdx.x;
  int n0 = blockIdx.x * 4;
  int w = t >> 6, lane = t & 63, q = lane & 31, half = lane >> 5;

  {
    int r = t >> 2;
    int kc = (t & 3) * 16;
    int node = n0 + (r >> 4);
    int jn = idx[node * 16 + (r & 15)];
    const float* pa = ab + node * 128 + kc;
    const float* pb = ab + jn * 128 + 64 + kc;
    const float* p1 = b1g + kc;
#pragma unroll
    for (int e4 = 0; e4 < 4; ++e4) {
      float4 va = *(const float4*)(pa + e4 * 4);
      float4 vb = *(const float4*)(pb + e4 * 4);
      float4 v1 = *(const float4*)(p1 + e4 * 4);
      float vals[4] = {va.x + vb.x + v1.x, va.y + vb.y + v1.y,
                       va.z + vb.z + v1.z, va.w + vb.w + v1.w};
      unsigned short hs[4], ls[4];
#pragma unroll
      for (int i = 0; i < 4; ++i) {
        float v = fmaxf(vals[i], 0.f);
        hs[i] = f2bf_rne(v);
        ls[i] = f2bf_rne(v - bf2f(hs[i]));
      }
      int off = r * 68 + kc + e4 * 4;
      *(u64*)&h1H[off] = ((u64)hs[0]) | ((u64)hs[1] << 16) | ((u64)hs[2] << 32) | ((u64)hs[3] << 48);
      *(u64*)&h1L[off] = ((u64)ls[0]) | ((u64)ls[1] << 16) | ((u64)ls[2] << 32) | ((u64)ls[3] << 48);
    }
  }

  bshort8 c2H[4], c2L[4];
#pragma unroll
  for (int ks = 0; ks < 4; ++ks) {
    c2H[ks] = w2fH[(w * 4 + ks) * 64 + lane];
    c2L[ks] = w2fL[(w * 4 + ks) * 64 + lane];
  }
  bshort8 c3H[8], c3L[8];
#pragma unroll
  for (int ks = 0; ks < 8; ++ks) {
    c3H[ks] = w3fH[(w * 8 + ks) * 64 + lane];
    c3L[ks] = w3fL[(w * 8 + ks) * 64 + lane];
  }
  float bias2 = b2g[w * 32 + q];
  float bias3 = b3g[w * 32 + q];
  __syncthreads();

#pragma unroll
  for (int rt = 0; rt < 2; ++rt) {
    f32x16 acc;
#pragma unroll
    for (int r = 0; r < 16; ++r) acc[r] = 0.f;
#pragma unroll
    for (int ks = 0; ks < 4; ++ks) {
      int off = (rt * 32 + q) * 68 + ks * 16 + half * 8;
      union { bshort8 v; u64 u[2]; } aH, aL;
      aH.u[0] = *(const u64*)&h1H[off];
      aH.u[1] = *(const u64*)&h1H[off + 4];
      aL.u[0] = *(const u64*)&h1L[off];
      aL.u[1] = *(const u64*)&h1L[off + 4];
      acc = __builtin_amdgcn_mfma_f32_32x32x16_bf16(aL.v, c2H[ks], acc, 0, 0, 0);
      acc = __builtin_amdgcn_mfma_f32_32x32x16_bf16(aH.v, c2L[ks], acc, 0, 0, 0);
      acc = __builtin_amdgcn_mfma_f32_32x32x16_bf16(aH.v, c2H[ks], acc, 0, 0, 0);
    }
#pragma unroll
    for (int reg = 0; reg < 16; ++reg) {
      int row = rt * 32 + (reg & 3) + 8 * (reg >> 2) + 4 * half;
      float v = fmaxf(acc[reg] + bias2, 0.f);
      unsigned short hb = f2bf_rne(v);
      h2H[row * 132 + w * 32 + q] = (short)hb;
      h2L[row * 132 + w * 32 + q] = (short)f2bf_rne(v - bf2f(hb));
    }
  }
  __syncthreads();

#pragma unroll
  for (int rt = 0; rt < 2; ++rt) {
    f32x16 acc;
#pragma unroll
    for (int r = 0; r < 16; ++r) acc[r] = 0.f;
#pragma unroll
    for (int ks = 0; ks < 8; ++ks) {
      int off = (rt * 32 + q) * 132 + ks * 16 + half * 8;
      union { bshort8 v; u64 u[2]; } aH, aL;
      aH.u[0] = *(const u64*)&h2H[off];
      aH.u[1] = *(const u64*)&h2H[off + 4];
      aL.u[0] = *(const u64*)&h2L[off];
      aL.u[1] = *(const u64*)&h2L[off + 4];
      acc = __builtin_amdgcn_mfma_f32_32x32x16_bf16(aL.v, c3H[ks], acc, 0, 0, 0);
      acc = __builtin_amdgcn_mfma_f32_32x32x16_bf16(aH.v, c3L[ks], acc, 0, 0, 0);
      acc = __builtin_amdgcn_mfma_f32_32x32x16_bf16(aH.v, c3H[ks], acc, 0, 0, 0);
    }
    float mA = -INFINITY, mB = -INFINITY;
#pragma unroll
    for (int reg = 0; reg < 8; ++reg) mA = fmaxf(mA, acc[reg]);
#pragma unroll
    for (int reg = 8; reg < 16; ++reg) mB = fmaxf(mB, acc[reg]);
    mA = fmaxf(mA, __shfl_xor(mA, 32, 64));
    mB = fmaxf(mB, __shfl_xor(mB, 32, 64));
    int col = w * 32 + q;
    int nodeA = n0 + rt * 2, nodeB = n0 + rt * 2 + 1;
    if (half == 0) {
      float v = mA + bias3;
      if (nadd) v += nadd[nodeA * 128 + col];
      eout[nodeA * 128 + col] = v;
    } else {
      float v = mB + bias3;
      if (nadd) v += nadd[nodeB * 128 + col];
      eout[nodeB * 128 + col] = v;
    }
  }
}

// ---------------- small epilogues ----------------
__global__ void k_e1n1(const float* __restrict__ e1, const float* __restrict__ n1,
                       float* s1) {
  int t = threadIdx.x;
  int node = blockIdx.x * 4 + (t >> 6);
  int lane = t & 63;
  float v0 = e1[node * 128 + lane] + n1[node * 128 + lane];
  float v1 = e1[node * 128 + 64 + lane] + n1[node * 128 + 64 + lane];
  float ss = v0 * v0 + v1 * v1;
#pragma unroll
  for (int off = 32; off; off >>= 1) ss += __shfl_down(ss, off, 64);
  if (lane == 0) s1[node] = sqrtf(ss);
}

__global__ void k_final(const float* __restrict__ s1, const float* __restrict__ e2n2,
                        const float* __restrict__ e3n3, float* __restrict__ out) {
  int t = threadIdx.x;
  int node = blockIdx.x * 4 + (t >> 6);
  int lane = t & 63;
  float s = s1[node];
  float z0 = s * e2n2[node * 128 + lane] * e3n3[node * 128 + lane];
  float z1 = s * e2n2[node * 128 + 64 + lane] * e3n3[node * 128 + 64 + lane];
  float m = fmaxf(z0, z1);
#pragma unroll
  for (int off = 32; off; off >>= 1) m = fmaxf(m, __shfl_xor(m, off, 64));
  float ex = expf(z0 - m) + expf(z1 - m);
#pragma unroll
  for (int off = 32; off; off >>= 1) ex += __shfl_xor(ex, off, 64);
  float lse = m + logf(ex);
  out[node * 128 + lane] = z0 - lse;
  out[node * 128 + 64 + lane] = z1 - lse;
}

// ---------------- host ----------------
extern "C" void kernel_launch(void* const* d_in, const int* in_sizes, int n_in,
                              void* d_out, int out_size, void* d_ws, size_t ws_size,
                              hipStream_t stream) {
  (void)in_sizes; (void)n_in; (void)out_size;
  const float* x  = (const float*)d_in[0];
  const int* ei   = (const int*)d_in[1];
  const float* ew = (const float*)d_in[2];
  const float* wg[3] = {(const float*)d_in[3], (const float*)d_in[5], (const float*)d_in[7]};
  const float* bg[3] = {(const float*)d_in[4], (const float*)d_in[6], (const float*)d_in[8]};
  const float* ew1[3] = {(const float*)d_in[9],  (const float*)d_in[15], (const float*)d_in[21]};
  const float* eb1[3] = {(const float*)d_in[10], (const float*)d_in[16], (const float*)d_in[22]};
  const float* ew2[3] = {(const float*)d_in[11], (const float*)d_in[17], (const float*)d_in[23]};
  const float* eb2[3] = {(const float*)d_in[12], (const float*)d_in[18], (const float*)d_in[24]};
  const float* ew3[3] = {(const float*)d_in[13], (const float*)d_in[19], (const float*)d_in[25]};
  const float* eb3[3] = {(const float*)d_in[14], (const float*)d_in[20], (const float*)d_in[26]};

  size_t small = (size_t)(23 * N_ + (N_ + 256) + N_ + 2 * E_);
  size_t need = (small + 172032 + (size_t)7 * N_ * H_) * sizeof(float);
  if (ws_size < need) return;

  float* ws  = (float*)d_ws;
  float* dis = ws;
  float* sn  = ws + N_;
  float* S1  = ws + 2 * N_;
  int* idx   = (int*)(ws + 3 * N_);
  int* cursor = (int*)(ws + 21 * N_);
  float* tauD = ws + 22 * N_;
  int* rowptr = (int*)(ws + 23 * N_);
  int* hist   = rowptr + N_ + 256;
  int* srcS   = hist + N_;
  float* normS = (float*)(srcS + E_);
  bshort8* wAll = (bshort8*)(normS + E_);     // 3 x 14336 bshort8
  float* h   = (float*)(normS + E_ + 172032);
  float* n1  = h + N_ * H_;
  float* n2  = n1 + N_ * H_;
  float* n3  = n2 + N_ * H_;
  float* E2  = n3 + N_ * H_;
  float* E1  = E2 + N_ * H_;
  float* ab  = E1 + N_ * H_;

  bshort8* fragHi = (bshort8*)h;
  bshort8* fragLo = (bshort8*)(h + N_ * H_ / 2);
  u64* candR  = (u64*)E1;                      // 128 rows over E1+ab (dead after tauseedX)
  u64* accept = (u64*)E1;                      // rows 0..127

  float* nl[3] = {n1, n2, n3};
  float* spare[3] = {n2, n1, n2};              // accExt rows 128..191, dead per layer
  float* nadd[3] = {nullptr, n2, n3};

  k_deg_init<<<N_ / 256, 256, 0, stream>>>(dis);
  k_deg_scatter<<<E_ / 256, 256, 0, stream>>>(ei, ew, dis);
  k_dis<<<N_ / 256, 256, 0, stream>>>(dis);
  hipMemsetAsync(hist, 0, N_ * sizeof(int), stream);
  k_hist<<<E_ / 256, 256, 0, stream>>>(ei, hist);
  k_scan<<<1, 256, 0, stream>>>(hist, rowptr);
  k_edgebuild<<<E_ / 256, 256, 0, stream>>>(ei, ew, dis, hist, srcS, normS);

  WP wp;
  for (int l = 0; l < 3; ++l) {
    wp.p[l * 4 + 0] = wg[l];
    wp.p[l * 4 + 1] = ew1[l];
    wp.p[l * 4 + 2] = ew2[l];
    wp.p[l * 4 + 3] = ew3[l];
  }
  k_wprepAll<<<84, 256, 0, stream>>>(wp, wAll);

  for (int l = 0; l < 3; ++l) {
    bshort8* wl = wAll + l * 14336;
    bshort8* wgfH = wl;            bshort8* wgfL = wl + 2048;
    bshort8* w1fH = wl + 4096;     bshort8* w1fL = wl + 6144;
    bshort8* w2fH = wl + 8192;     bshort8* w2fL = wl + 9216;
    bshort8* w3fH = wl + 10240;    bshort8* w3fL = wl + 12288;

    const float* inp = (l == 0) ? x : nl[l - 1];
    k_gemmM<<<256, 256, 0, stream>>>(inp, wgfH, wgfL, h);
    k_gcn_agg<<<N_ / 2, 256, 0, stream>>>(h, dis, rowptr, srcS, normS, bg[l], nl[l], sn);
    k_fragprep<<<N_ * 16 / 256, 256, 0, stream>>>(nl[l], fragHi, fragLo);
    k_knnA<<<dim3(N_ / 32, 4), 256, 0, stream>>>(fragHi, fragLo, sn, candR);
    k_tauseedX<<<N_ / 64, 256, 0, stream>>>(candR, cursor, tauD);
    k_knnB<<<dim3(N_ / 128, 8), 256, 0, stream>>>(fragHi, fragLo, sn, tauD, cursor,
                                                  accept, (u64*)spare[l]);
    k_select<<<N_ / 64, 256, 0, stream>>>(accept, (u64*)spare[l], cursor, idx);
    k_gemmMF<<<512, 128, 0, stream>>>(fragHi, fragLo, w1fH, w1fL, ab);
    float* etgt = (l == 1) ? E2 : E1;
    k_mlpM<<<N_ / 4, 256, 0, stream>>>(ab, idx, w2fH, w2fL, w3fH, w3fL,
                                       eb1[l], eb2[l], eb3[l], nadd[l], etgt);
    if (l == 0) k_e1n1<<<N_ / 4, 256, 0, stream>>>(E1, n1, S1);
  }
  k_final<<<N_ / 4, 256, 0, stream>>>(S1, E2, E1, (float*)d_out);
}

// Round 16
// 800.981 us; speedup vs baseline: 1.0511x; 1.0511x over previous
//
#include <hip/hip_runtime.h>
#include <math.h>

#define N_ 8192
#define H_ 128
#define E_ 262144
#define K_ 16
#define SLABJ 1024
#define CHUNKJ 512

typedef __attribute__((ext_vector_type(8))) short bshort8;
typedef __attribute__((ext_vector_type(16))) float f32x16;
typedef unsigned long long u64;

// ---------------- degree / normalization ----------------
__global__ void k_deg_init(float* deg) {
  int i = blockIdx.x * 256 + threadIdx.x;
  deg[i] = 1.0f;
}

__global__ void k_deg_scatter(const int* __restrict__ ei, const float* __restrict__ ew,
                              float* deg) {
  int e = blockIdx.x * 256 + threadIdx.x;
  atomicAdd(&deg[ei[E_ + e]], ew[e]);
}

__global__ void k_dis(float* deg) {
  int i = blockIdx.x * 256 + threadIdx.x;
  deg[i] = rsqrtf(deg[i]);
}

// ---------------- one-time CSR build ----------------
__global__ void k_hist(const int* __restrict__ ei, int* hist) {
  int e = blockIdx.x * 256 + threadIdx.x;
  atomicAdd(&hist[ei[E_ + e]], 1);
}

__global__ void k_scan(int* hist, int* rowptr) {
  __shared__ int part[256];
  __shared__ int partx[257];
  int t = threadIdx.x;
  int base = t * 32;
  int loc[32];
  int s = 0;
#pragma unroll
  for (int i = 0; i < 32; ++i) { loc[i] = s; s += hist[base + i]; }
  part[t] = s;
  __syncthreads();
  if (t == 0) {
    int r = 0;
    for (int i = 0; i < 256; ++i) { partx[i] = r; r += part[i]; }
    partx[256] = r;
  }
  __syncthreads();
  int b = partx[t];
#pragma unroll
  for (int i = 0; i < 32; ++i) {
    rowptr[base + i] = b + loc[i];
    hist[base + i] = b + loc[i];
  }
  if (t == 0) rowptr[N_] = partx[256];
}

__global__ void k_edgebuild(const int* __restrict__ ei, const float* __restrict__ ew,
                            const float* __restrict__ dis, int* cursor,
                            int* __restrict__ srcS, float* __restrict__ normS) {
  int e = blockIdx.x * 256 + threadIdx.x;
  int s = ei[e], d = ei[E_ + e];
  int pos = atomicAdd(&cursor[d], 1);
  srcS[pos] = s;
  normS[pos] = dis[s] * ew[e] * dis[d];
}

// ---------------- bf16 helpers ----------------
__device__ __forceinline__ unsigned short f2bf_rne(float x) {
  unsigned u = __builtin_bit_cast(unsigned, x);
  unsigned r = ((u >> 16) & 1u) + 0x7fffu;
  return (unsigned short)((u + r) >> 16);
}
__device__ __forceinline__ float bf2f(unsigned short b) {
  unsigned u = ((unsigned)b) << 16;
  return __builtin_bit_cast(float, u);
}

// ---------------- one-shot weight frag prep (all 3 layers) ----------------
struct WP { const float* p[12]; };  // per layer: wg, ew1, ew2, ew3

__global__ void k_wprepAll(WP wp, bshort8* __restrict__ wAll) {
  int id = blockIdx.x * 256 + threadIdx.x;  // 21504
  int layer = id / 7168;
  int r = id - layer * 7168;
  bshort8* base = wAll + layer * 14336;
  const float* src;
  bshort8 *dH, *dL;
  int slot, kind;
  if (r < 2048)      { kind = 0; slot = r;        src = wp.p[layer*4+0]; dH = base;         dL = base + 2048; }
  else if (r < 4096) { kind = 1; slot = r - 2048; src = wp.p[layer*4+1]; dH = base + 4096;  dL = base + 6144; }
  else if (r < 5120) { kind = 2; slot = r - 4096; src = wp.p[layer*4+2]; dH = base + 8192;  dL = base + 9216; }
  else               { kind = 3; slot = r - 5120; src = wp.p[layer*4+3]; dH = base + 10240; dL = base + 12288; }
  int lane = slot & 63;
  int n, k0;
  if (kind == 2) {
    int ks = (slot >> 6) & 3, nt = slot >> 8;
    n = nt * 32 + (lane & 31);
    k0 = ks * 16 + (lane >> 5) * 8;
  } else {
    int ks = (slot >> 6) & 7, nt = slot >> 9;
    n = nt * 32 + (lane & 31);
    k0 = ks * 16 + (lane >> 5) * 8;
  }
  bshort8 h, l;
#pragma unroll
  for (int i = 0; i < 8; ++i) {
    int k = k0 + i;
    float v;
    if (kind == 1) v = (n < 64) ? (src[k * 64 + n] - src[(128 + k) * 64 + n])
                                : src[(128 + k) * 64 + (n - 64)];
    else v = src[k * 128 + n];
    unsigned short hb = f2bf_rne(v);
    h[i] = (short)hb;
    l[i] = (short)f2bf_rne(v - bf2f(hb));
  }
  dH[slot] = h;
  dL[slot] = l;
}

// ---------------- MFMA GEMM: [8192x128] @ [128x128], fp32 A (staged) ----------------
__global__ __launch_bounds__(256, 3) void k_gemmM(const float* __restrict__ A,
                                                  const bshort8* __restrict__ wfH,
                                                  const bshort8* __restrict__ wfL,
                                                  float* __restrict__ C) {
  __shared__ short aHs[32 * 132], aLs[32 * 132];
  int t = threadIdx.x;
  int r0 = blockIdx.x * 32;
  int w = t >> 6, lane = t & 63, q = lane & 31, half = lane >> 5;

  {
    int r = t >> 3;
    int kc = (t & 7) * 16;
    const float* p = A + (r0 + r) * 128 + kc;
#pragma unroll
    for (int e4 = 0; e4 < 4; ++e4) {
      float4 v = *(const float4*)(p + e4 * 4);
      float vals[4] = {v.x, v.y, v.z, v.w};
      unsigned short hs[4], ls[4];
#pragma unroll
      for (int i = 0; i < 4; ++i) {
        hs[i] = f2bf_rne(vals[i]);
        ls[i] = f2bf_rne(vals[i] - bf2f(hs[i]));
      }
      int off = r * 132 + kc + e4 * 4;
      *(u64*)&aHs[off] = ((u64)hs[0]) | ((u64)hs[1] << 16) | ((u64)hs[2] << 32) | ((u64)hs[3] << 48);
      *(u64*)&aLs[off] = ((u64)ls[0]) | ((u64)ls[1] << 16) | ((u64)ls[2] << 32) | ((u64)ls[3] << 48);
    }
  }
  bshort8 bH[8], bL[8];
#pragma unroll
  for (int ks = 0; ks < 8; ++ks) {
    bH[ks] = wfH[(w * 8 + ks) * 64 + lane];
    bL[ks] = wfL[(w * 8 + ks) * 64 + lane];
  }
  __syncthreads();

  f32x16 accP, accQ;
#pragma unroll
  for (int r = 0; r < 16; ++r) { accP[r] = 0.f; accQ[r] = 0.f; }
#pragma unroll
  for (int ks = 0; ks < 8; ++ks) {
    int off = q * 132 + ks * 16 + half * 8;
    union { bshort8 v; u64 u[2]; } aH, aL;
    aH.u[0] = *(const u64*)&aHs[off];
    aH.u[1] = *(const u64*)&aHs[off + 4];
    aL.u[0] = *(const u64*)&aLs[off];
    aL.u[1] = *(const u64*)&aLs[off + 4];
    accQ = __builtin_amdgcn_mfma_f32_32x32x16_bf16(aL.v, bH[ks], accQ, 0, 0, 0);
    accQ = __builtin_amdgcn_mfma_f32_32x32x16_bf16(aH.v, bL[ks], accQ, 0, 0, 0);
    accP = __builtin_amdgcn_mfma_f32_32x32x16_bf16(aH.v, bH[ks], accP, 0, 0, 0);
  }
#pragma unroll
  for (int reg = 0; reg < 16; ++reg) {
    int row = (reg & 3) + 8 * (reg >> 2) + 4 * half;
    C[(r0 + row) * 128 + w * 32 + q] = accP[reg] + accQ[reg];
  }
}

// ---------------- MFMA GEMM, frag-A input (no staging) ----------------
__global__ void k_gemmMF(const bshort8* __restrict__ fAH, const bshort8* __restrict__ fAL,
                         const bshort8* __restrict__ wfH, const bshort8* __restrict__ wfL,
                         float* __restrict__ C) {
  int t = threadIdx.x;
  int rt = blockIdx.x >> 1;
  int w = (blockIdx.x & 1) * 2 + (t >> 6);
  int lane = t & 63, q = lane & 31, half = lane >> 5;

  bshort8 bH[8], bL[8], aH[8], aL[8];
#pragma unroll
  for (int ks = 0; ks < 8; ++ks) {
    bH[ks] = wfH[(w * 8 + ks) * 64 + lane];
    bL[ks] = wfL[(w * 8 + ks) * 64 + lane];
    aH[ks] = fAH[(rt * 8 + ks) * 64 + lane];
    aL[ks] = fAL[(rt * 8 + ks) * 64 + lane];
  }
  f32x16 accP, accQ;
#pragma unroll
  for (int r = 0; r < 16; ++r) { accP[r] = 0.f; accQ[r] = 0.f; }
#pragma unroll
  for (int ks = 0; ks < 8; ++ks) {
    accQ = __builtin_amdgcn_mfma_f32_32x32x16_bf16(aL[ks], bH[ks], accQ, 0, 0, 0);
    accQ = __builtin_amdgcn_mfma_f32_32x32x16_bf16(aH[ks], bL[ks], accQ, 0, 0, 0);
    accP = __builtin_amdgcn_mfma_f32_32x32x16_bf16(aH[ks], bH[ks], accP, 0, 0, 0);
  }
#pragma unroll
  for (int reg = 0; reg < 16; ++reg) {
    int row = (reg & 3) + 8 * (reg >> 2) + 4 * half;
    C[(rt * 32 + row) * 128 + w * 32 + q] = accP[reg] + accQ[reg];
  }
}

// ---------------- fused GCN aggregation (CSR gather) ----------------
__global__ __launch_bounds__(256) void k_gcn_agg(const float* __restrict__ h,
                                                 const float* __restrict__ dis,
                                                 const int* __restrict__ rowptr,
                                                 const int* __restrict__ srcS,
                                                 const float* __restrict__ normS,
                                                 const float* __restrict__ bg,
                                                 float* __restrict__ n_out,
                                                 float* __restrict__ sn) {
  __shared__ float part[4];
  int t = threadIdx.x;
  int i = blockIdx.x * 2 + (t >> 7);
  int c = t & 127;
  float di = dis[i];
  float a0 = di * di * h[i * 128 + c], a1 = 0.f, a2 = 0.f, a3 = 0.f;
  int e0 = rowptr[i], e1 = rowptr[i + 1];
  int e = e0;
  for (; e + 4 <= e1; e += 4) {
    int s0 = srcS[e], s1 = srcS[e + 1], s2 = srcS[e + 2], s3 = srcS[e + 3];
    float w0 = normS[e], w1 = normS[e + 1], w2 = normS[e + 2], w3 = normS[e + 3];
    a0 += w0 * h[s0 * 128 + c];
    a1 += w1 * h[s1 * 128 + c];
    a2 += w2 * h[s2 * 128 + c];
    a3 += w3 * h[s3 * 128 + c];
  }
  for (; e < e1; ++e) a0 += normS[e] * h[srcS[e] * 128 + c];
  float v = tanhf(a0 + a1 + a2 + a3 + bg[c]);
  n_out[i * 128 + c] = v;
  float vv = v * v;
#pragma unroll
  for (int off = 32; off; off >>= 1) vv += __shfl_down(vv, off, 64);
  if ((t & 63) == 0) part[t >> 6] = vv;
  __syncthreads();
  if ((t & 127) == 0) sn[i] = part[t >> 6] + part[(t >> 6) + 1];
}

// ---------------- feature frag prep ----------------
__global__ void k_fragprep(const float* __restrict__ src, bshort8* __restrict__ hiA,
                           bshort8* __restrict__ loA) {
  int t = blockIdx.x * 256 + threadIdx.x;
  int j = t >> 4, slot = t & 15;
  const float* p = src + j * 128 + slot * 8;
  float4 f0 = *(const float4*)p;
  float4 f1 = *(const float4*)(p + 4);
  float f[8] = {f0.x, f0.y, f0.z, f0.w, f1.x, f1.y, f1.z, f1.w};
  bshort8 h, l;
#pragma unroll
  for (int i = 0; i < 8; ++i) {
    unsigned short hb = f2bf_rne(f[i]);
    h[i] = (short)hb;
    l[i] = (short)f2bf_rne(f[i] - bf2f(hb));
  }
  int ks = slot >> 1, half = slot & 1;
  int dst = ((j >> 5) * 8 + ks) * 64 + half * 32 + (j & 31);
  hiA[dst] = h;
  loA[dst] = l;
}

// ---------------- packed-key helpers ----------------
__device__ __forceinline__ u64 packkey(float d, int j) {
  unsigned m = __builtin_bit_cast(unsigned, d);
  m = (m & 0x80000000u) ? ~m : (m | 0x80000000u);
  return (((u64)m) << 32) | (unsigned)j;
}

__device__ __forceinline__ float unpackd(u64 key) {
  unsigned m = (unsigned)(key >> 32);
  unsigned u = (m & 0x80000000u) ? (m & 0x7fffffffu) : ~m;
  return __builtin_bit_cast(float, u);
}

__device__ __forceinline__ void ins4(u64* tk, u64 x) {
  bool c[4];
#pragma unroll
  for (int s = 0; s < 4; ++s) c[s] = x < tk[s];
#pragma unroll
  for (int s = 3; s >= 1; --s) tk[s] = c[s - 1] ? tk[s - 1] : (c[s] ? x : tk[s]);
  tk[0] = c[0] ? x : tk[0];
}

__device__ __forceinline__ void ins16(u64* tk, u64 x) {
  bool c[16];
#pragma unroll
  for (int s = 0; s < 16; ++s) c[s] = x < tk[s];
#pragma unroll
  for (int s = 15; s >= 1; --s) tk[s] = c[s - 1] ? tk[s - 1] : (c[s] ? x : tk[s]);
  tk[0] = c[0] ? x : tk[0];
}

// ---------------- phase A (tau bound only): 4 chunks x 512 j, per-lane sorted-4 ----------------
// Software-pipelined: half-tile prefetch across the epilogue boundary.
__global__ __launch_bounds__(256, 2) void k_knnA(const bshort8* __restrict__ fragHi,
                                                 const bshort8* __restrict__ fragLo,
                                                 const float* __restrict__ sn,
                                                 u64* __restrict__ candR) {
  __shared__ float snS[CHUNKJ];
  int t = threadIdx.x;
  int qtile = blockIdx.x, chunk = blockIdx.y;
  int wave = t >> 6, lane = t & 63;
  int q = lane & 31, half = lane >> 5;

  snS[t] = sn[chunk * CHUNKJ + t];
  snS[t + 256] = sn[chunk * CHUNKJ + t + 256];

  bshort8 bHi[8], bLo[8];
#pragma unroll
  for (int ks = 0; ks < 8; ++ks) {
    int o = (qtile * 8 + ks) * 64 + lane;
    bHi[ks] = fragHi[o];
    bLo[ks] = fragLo[o];
  }
  __syncthreads();

  u64 tk[4];
#pragma unroll
  for (int s = 0; s < 4; ++s) tk[s] = ~0ULL;

  int jt0 = chunk * 16 + wave * 4;
  bshort8 pH[4], pL[4];
#pragma unroll
  for (int k4 = 0; k4 < 4; ++k4) {
    int o = (jt0 * 8 + k4) * 64 + lane;
    pH[k4] = fragHi[o];
    pL[k4] = fragLo[o];
  }

  for (int ti = 0; ti < 4; ++ti) {
    int jt = jt0 + ti;
    f32x16 accP, accQ;
#pragma unroll
    for (int r = 0; r < 16; ++r) { accP[r] = 0.f; accQ[r] = 0.f; }

    // prefetch half 1 of this tile
    bshort8 qH[4], qL[4];
#pragma unroll
    for (int k4 = 0; k4 < 4; ++k4) {
      int o = (jt * 8 + 4 + k4) * 64 + lane;
      qH[k4] = fragHi[o];
      qL[k4] = fragLo[o];
    }
    // consume half 0
#pragma unroll
    for (int k4 = 0; k4 < 4; ++k4) {
      accQ = __builtin_amdgcn_mfma_f32_32x32x16_bf16(pL[k4], bHi[k4], accQ, 0, 0, 0);
      accQ = __builtin_amdgcn_mfma_f32_32x32x16_bf16(pH[k4], bLo[k4], accQ, 0, 0, 0);
      accP = __builtin_amdgcn_mfma_f32_32x32x16_bf16(pH[k4], bHi[k4], accP, 0, 0, 0);
    }
    // prefetch half 0 of next tile (before epilogue)
    if (ti < 3) {
#pragma unroll
      for (int k4 = 0; k4 < 4; ++k4) {
        int o = ((jt + 1) * 8 + k4) * 64 + lane;
        pH[k4] = fragHi[o];
        pL[k4] = fragLo[o];
      }
    }
    // consume half 1
#pragma unroll
    for (int k4 = 0; k4 < 4; ++k4) {
      accQ = __builtin_amdgcn_mfma_f32_32x32x16_bf16(qL[k4], bHi[4 + k4], accQ, 0, 0, 0);
      accQ = __builtin_amdgcn_mfma_f32_32x32x16_bf16(qH[k4], bLo[4 + k4], accQ, 0, 0, 0);
      accP = __builtin_amdgcn_mfma_f32_32x32x16_bf16(qH[k4], bHi[4 + k4], accP, 0, 0, 0);
    }

    int jbase = (wave * 4 + ti) * 32;
#pragma unroll
    for (int rp = 0; rp < 8; ++rp) {
      int r0 = rp * 2;
      int row0 = (r0 & 3) + 8 * (r0 >> 2) + 4 * half;
      float d0 = snS[jbase + row0] - 2.0f * (accP[r0] + accQ[r0]);
      float d1 = snS[jbase + row0 + 1] - 2.0f * (accP[r0 + 1] + accQ[r0 + 1]);
      u64 k0 = packkey(d0, chunk * CHUNKJ + jbase + row0);
      u64 k1 = packkey(d1, chunk * CHUNKJ + jbase + row0 + 1);
      u64 km = k0 < k1 ? k0 : k1;
      if (km < tk[3]) {
        if (k0 < tk[3]) ins4(tk, k0);
        if (k1 < tk[3]) ins4(tk, k1);
      }
    }
  }

  int g = wave * 2 + half;
#pragma unroll
  for (int s = 0; s < 4; ++s)
    candR[(size_t)(chunk * 32 + g * 4 + s) * N_ + qtile * 32 + q] = tk[s];
}

// tau = 16th smallest of 32 sorted-4 lists (upper bound; truncation only loosens)
__global__ __launch_bounds__(256) void k_tauseedX(const u64* __restrict__ candR,
                                                  int* __restrict__ cursor,
                                                  float* __restrict__ tauD) {
  __shared__ u64 mb[64 * 65];
  int t = threadIdx.x;
  int ql = t >> 2, j = t & 3;
  int q = blockIdx.x * 64 + ql;

  int rb[8];
#pragma unroll
  for (int k = 0; k < 8; ++k) {
    int L = 8 * j + k;
    rb[k] = (L >> 3) * 32 + (L & 7) * 4;
  }
  int h0 = 0, h1 = 0, h2 = 0, h3 = 0, h4 = 0, h5 = 0, h6 = 0, h7 = 0;
  for (int step = 0; step < 16; ++step) {
    u64 best = (h0 < 4) ? candR[(size_t)(rb[0] + h0) * N_ + q] : ~0ULL;
    int bg = 0;
    u64 b;
    b = (h1 < 4) ? candR[(size_t)(rb[1] + h1) * N_ + q] : ~0ULL; if (b < best) { best = b; bg = 1; }
    b = (h2 < 4) ? candR[(size_t)(rb[2] + h2) * N_ + q] : ~0ULL; if (b < best) { best = b; bg = 2; }
    b = (h3 < 4) ? candR[(size_t)(rb[3] + h3) * N_ + q] : ~0ULL; if (b < best) { best = b; bg = 3; }
    b = (h4 < 4) ? candR[(size_t)(rb[4] + h4) * N_ + q] : ~0ULL; if (b < best) { best = b; bg = 4; }
    b = (h5 < 4) ? candR[(size_t)(rb[5] + h5) * N_ + q] : ~0ULL; if (b < best) { best = b; bg = 5; }
    b = (h6 < 4) ? candR[(size_t)(rb[6] + h6) * N_ + q] : ~0ULL; if (b < best) { best = b; bg = 6; }
    b = (h7 < 4) ? candR[(size_t)(rb[7] + h7) * N_ + q] : ~0ULL; if (b < best) { best = b; bg = 7; }
    mb[ql * 65 + j * 16 + step] = best;
    h0 += (bg == 0); h1 += (bg == 1); h2 += (bg == 2); h3 += (bg == 3);
    h4 += (bg == 4); h5 += (bg == 5); h6 += (bg == 6); h7 += (bg == 7);
  }
  __syncthreads();
  if (t < 64) {
    int qq = blockIdx.x * 64 + t;
    int base = t * 65;
    int g0 = 0, g1 = 0, g2 = 0, g3 = 0;
    u64 best = 0;
    for (int step = 0; step < 16; ++step) {
      best = mb[base + g0];
      int bg = 0;
      u64 b;
      b = mb[base + 16 + g1]; if (b < best) { best = b; bg = 1; }
      b = mb[base + 32 + g2]; if (b < best) { best = b; bg = 2; }
      b = mb[base + 48 + g3]; if (b < best) { best = b; bg = 3; }
      g0 += (bg == 0); g1 += (bg == 1); g2 += (bg == 2); g3 += (bg == 3);
    }
    tauD[qq] = unpackd(best);
    cursor[qq] = 0;
  }
}

// ---------------- phase B: ALL 8 slabs, pipelined registers, float filter ----------------
__global__ __launch_bounds__(256, 2) void k_knnB(const bshort8* __restrict__ fragHi,
                                                 const bshort8* __restrict__ fragLo,
                                                 const float* __restrict__ sn,
                                                 const float* __restrict__ tauD,
                                                 int* __restrict__ cursor,
                                                 u64* __restrict__ accept,
                                                 u64* __restrict__ accExt) {
  __shared__ float snS[SLABJ];
  int t = threadIdx.x;
  int qtile = blockIdx.x, slab = blockIdx.y;
  int wave = t >> 6, lane = t & 63;
  int q = lane & 31, half = lane >> 5;
  int qg = qtile * 32 + q;

#pragma unroll
  for (int p = 0; p < 4; ++p) snS[t + 256 * p] = sn[slab * SLABJ + t + 256 * p];

  bshort8 bHi[8], bLo[8];
#pragma unroll
  for (int ks = 0; ks < 8; ++ks) {
    int o = (qtile * 8 + ks) * 64 + lane;
    bHi[ks] = fragHi[o];
    bLo[ks] = fragLo[o];
  }
  float tD = tauD[qg];
  __syncthreads();

  u64 buf[6];
  int cnt = 0;

  int jt0 = slab * 32 + wave * 8;
  bshort8 pH[4], pL[4];
#pragma unroll
  for (int k4 = 0; k4 < 4; ++k4) {
    int o = (jt0 * 8 + k4) * 64 + lane;
    pH[k4] = fragHi[o];
    pL[k4] = fragLo[o];
  }

  for (int ti = 0; ti < 8; ++ti) {
    int jt = jt0 + ti;
    f32x16 accP, accQ;
#pragma unroll
    for (int r = 0; r < 16; ++r) { accP[r] = 0.f; accQ[r] = 0.f; }

    // prefetch half 1
    bshort8 qH[4], qL[4];
#pragma unroll
    for (int k4 = 0; k4 < 4; ++k4) {
      int o = (jt * 8 + 4 + k4) * 64 + lane;
      qH[k4] = fragHi[o];
      qL[k4] = fragLo[o];
    }
    // consume half 0
#pragma unroll
    for (int k4 = 0; k4 < 4; ++k4) {
      accQ = __builtin_amdgcn_mfma_f32_32x32x16_bf16(pL[k4], bHi[k4], accQ, 0, 0, 0);
      accQ = __builtin_amdgcn_mfma_f32_32x32x16_bf16(pH[k4], bLo[k4], accQ, 0, 0, 0);
      accP = __builtin_amdgcn_mfma_f32_32x32x16_bf16(pH[k4], bHi[k4], accP, 0, 0, 0);
    }
    // prefetch half 0 of next tile (before branchy epilogue)
    if (ti < 7) {
#pragma unroll
      for (int k4 = 0; k4 < 4; ++k4) {
        int o = ((jt + 1) * 8 + k4) * 64 + lane;
        pH[k4] = fragHi[o];
        pL[k4] = fragLo[o];
      }
    }
    // consume half 1
#pragma unroll
    for (int k4 = 0; k4 < 4; ++k4) {
      accQ = __builtin_amdgcn_mfma_f32_32x32x16_bf16(qL[k4], bHi[4 + k4], accQ, 0, 0, 0);
      accQ = __builtin_amdgcn_mfma_f32_32x32x16_bf16(qH[k4], bLo[4 + k4], accQ, 0, 0, 0);
      accP = __builtin_amdgcn_mfma_f32_32x32x16_bf16(qH[k4], bHi[4 + k4], accP, 0, 0, 0);
    }

    int jbase = (wave * 8 + ti) * 32;
#pragma unroll
    for (int rp = 0; rp < 8; ++rp) {
      int r0 = rp * 2;
      int row0 = (r0 & 3) + 8 * (r0 >> 2) + 4 * half;
      float d0 = snS[jbase + row0] - 2.0f * (accP[r0] + accQ[r0]);
      float d1 = snS[jbase + row0 + 1] - 2.0f * (accP[r0 + 1] + accQ[r0 + 1]);
      if (d0 <= tD) {
        u64 k0 = packkey(d0, slab * SLABJ + jbase + row0);
        if (cnt < 6) {
#pragma unroll
          for (int s = 0; s < 6; ++s)
            if (s == cnt) buf[s] = k0;
          ++cnt;
        } else {
          int pos = atomicAdd(&cursor[qg], 1);
          if (pos < 128) accept[(size_t)pos * N_ + qg] = k0;
          else if (pos < 192) accExt[(size_t)(pos - 128) * N_ + qg] = k0;
        }
      }
      if (d1 <= tD) {
        u64 k1 = packkey(d1, slab * SLABJ + jbase + row0 + 1);
        if (cnt < 6) {
#pragma unroll
          for (int s = 0; s < 6; ++s)
            if (s == cnt) buf[s] = k1;
          ++cnt;
        } else {
          int pos = atomicAdd(&cursor[qg], 1);
          if (pos < 128) accept[(size_t)pos * N_ + qg] = k1;
          else if (pos < 192) accExt[(size_t)(pos - 128) * N_ + qg] = k1;
        }
      }
    }
  }

  if (cnt > 0) {
    int pos = atomicAdd(&cursor[qg], cnt);
#pragma unroll
    for (int s = 0; s < 6; ++s) {
      if (s < cnt) {
        int slot = pos + s;
        if (slot < 128) accept[(size_t)slot * N_ + qg] = buf[s];
        else if (slot < 192) accExt[(size_t)(slot - 128) * N_ + qg] = buf[s];
      }
    }
  }
}

// ---------------- phase C: wave-parallel exact top-16 (4 lanes/query) ----------------
__global__ __launch_bounds__(256) void k_select(const u64* __restrict__ accept,
                                                const u64* __restrict__ accExt,
                                                const int* __restrict__ cursor,
                                                int* __restrict__ idxo) {
  __shared__ u64 mb[64 * 65];
  int t = threadIdx.x;
  int ql = t >> 2;
  int j = t & 3;
  int q = blockIdx.x * 64 + ql;
  int c = cursor[q];
  if (c > 192) c = 192;
  u64 tk[16];
#pragma unroll
  for (int s = 0; s < 16; ++s) tk[s] = ~0ULL;
  for (int i = j; i < c; i += 4) {
    u64 x = (i < 128) ? accept[(size_t)i * N_ + q] : accExt[(size_t)(i - 128) * N_ + q];
    if (x < tk[15]) ins16(tk, x);
  }
#pragma unroll
  for (int s = 0; s < 16; ++s) mb[ql * 65 + j * 16 + s] = tk[s];
  __syncthreads();
  if (t < 64) {
    int qq = blockIdx.x * 64 + t;
    int base = t * 65;
    int h0 = 0, h1 = 0, h2 = 0, h3 = 0;
    for (int step = 0; step < 16; ++step) {
      u64 best = mb[base + h0];
      int bg = 0;
      u64 b;
      b = mb[base + 16 + h1]; if (b < best) { best = b; bg = 1; }
      b = mb[base + 32 + h2]; if (b < best) { best = b; bg = 2; }
      b = mb[base + 48 + h3]; if (b < best) { best = b; bg = 3; }
      idxo[qq * 16 + step] = (int)(unsigned)(best & 0xffffffffULL);
      h0 += (bg == 0); h1 += (bg == 1); h2 += (bg == 2); h3 += (bg == 3);
    }
  }
}

// ---------------- MFMA EdgeConv MLP ----------------
__global__ __launch_bounds__(256, 3) void k_mlpM(
    const float* __restrict__ ab, const int* __restrict__ idx,
    const bshort8* __restrict__ w2fH, const bshort8* __restrict__ w2fL,
    const bshort8* __restrict__ w3fH, const bshort8* __restrict__ w3fL,
    const float* __restrict__ b1g, const float* __restrict__ b2g,
    const float* __restrict__ b3g, const float* __restrict__ nadd,
    float* __restrict__ eout) {
  __shared__ short h1H[64 * 68], h1L[64 * 68];
  __shared__ short h2H[64 * 132], h2L[64 * 132];
  int t = threadIdx.x;
  int n0 = blockIdx.x * 4;
  int w = t >> 6, lane = t & 63, q = lane & 31, half = lane >> 5;

  {
    int r = t >> 2;
    int kc = (t & 3) * 16;
    int node = n0 + (r >> 4);
    int jn = idx[node * 16 + (r & 15)];
    const float* pa = ab + node * 128 + kc;
    const float* pb = ab + jn * 128 + 64 + kc;
    const float* p1 = b1g + kc;
#pragma unroll
    for (int e4 = 0; e4 < 4; ++e4) {
      float4 va = *(const float4*)(pa + e4 * 4);
      float4 vb = *(const float4*)(pb + e4 * 4);
      float4 v1 = *(const float4*)(p1 + e4 * 4);
      float vals[4] = {va.x + vb.x + v1.x, va.y + vb.y + v1.y,
                       va.z + vb.z + v1.z, va.w + vb.w + v1.w};
      unsigned short hs[4], ls[4];
#pragma unroll
      for (int i = 0; i < 4; ++i) {
        float v = fmaxf(vals[i], 0.f);
        hs[i] = f2bf_rne(v);
        ls[i] = f2bf_rne(v - bf2f(hs[i]));
      }
      int off = r * 68 + kc + e4 * 4;
      *(u64*)&h1H[off] = ((u64)hs[0]) | ((u64)hs[1] << 16) | ((u64)hs[2] << 32) | ((u64)hs[3] << 48);
      *(u64*)&h1L[off] = ((u64)ls[0]) | ((u64)ls[1] << 16) | ((u64)ls[2] << 32) | ((u64)ls[3] << 48);
    }
  }

  bshort8 c2H[4], c2L[4];
#pragma unroll
  for (int ks = 0; ks < 4; ++ks) {
    c2H[ks] = w2fH[(w * 4 + ks) * 64 + lane];
    c2L[ks] = w2fL[(w * 4 + ks) * 64 + lane];
  }
  bshort8 c3H[8], c3L[8];
#pragma unroll
  for (int ks = 0; ks < 8; ++ks) {
    c3H[ks] = w3fH[(w * 8 + ks) * 64 + lane];
    c3L[ks] = w3fL[(w * 8 + ks) * 64 + lane];
  }
  float bias2 = b2g[w * 32 + q];
  float bias3 = b3g[w * 32 + q];
  __syncthreads();

#pragma unroll
  for (int rt = 0; rt < 2; ++rt) {
    f32x16 acc;
#pragma unroll
    for (int r = 0; r < 16; ++r) acc[r] = 0.f;
#pragma unroll
    for (int ks = 0; ks < 4; ++ks) {
      int off = (rt * 32 + q) * 68 + ks * 16 + half * 8;
      union { bshort8 v; u64 u[2]; } aH, aL;
      aH.u[0] = *(const u64*)&h1H[off];
      aH.u[1] = *(const u64*)&h1H[off + 4];
      aL.u[0] = *(const u64*)&h1L[off];
      aL.u[1] = *(const u64*)&h1L[off + 4];
      acc = __builtin_amdgcn_mfma_f32_32x32x16_bf16(aL.v, c2H[ks], acc, 0, 0, 0);
      acc = __builtin_amdgcn_mfma_f32_32x32x16_bf16(aH.v, c2L[ks], acc, 0, 0, 0);
      acc = __builtin_amdgcn_mfma_f32_32x32x16_bf16(aH.v, c2H[ks], acc, 0, 0, 0);
    }
#pragma unroll
    for (int reg = 0; reg < 16; ++reg) {
      int row = rt * 32 + (reg & 3) + 8 * (reg >> 2) + 4 * half;
      float v = fmaxf(acc[reg] + bias2, 0.f);
      unsigned short hb = f2bf_rne(v);
      h2H[row * 132 + w * 32 + q] = (short)hb;
      h2L[row * 132 + w * 32 + q] = (short)f2bf_rne(v - bf2f(hb));
    }
  }
  __syncthreads();

#pragma unroll
  for (int rt = 0; rt < 2; ++rt) {
    f32x16 acc;
#pragma unroll
    for (int r = 0; r < 16; ++r) acc[r] = 0.f;
#pragma unroll
    for (int ks = 0; ks < 8; ++ks) {
      int off = (rt * 32 + q) * 132 + ks * 16 + half * 8;
      union { bshort8 v; u64 u[2]; } aH, aL;
      aH.u[0] = *(const u64*)&h2H[off];
      aH.u[1] = *(const u64*)&h2H[off + 4];
      aL.u[0] = *(const u64*)&h2L[off];
      aL.u[1] = *(const u64*)&h2L[off + 4];
      acc = __builtin_amdgcn_mfma_f32_32x32x16_bf16(aL.v, c3H[ks], acc, 0, 0, 0);
      acc = __builtin_amdgcn_mfma_f32_32x32x16_bf16(aH.v, c3L[ks], acc, 0, 0, 0);
      acc = __builtin_amdgcn_mfma_f32_32x32x16_bf16(aH.v, c3H[ks], acc, 0, 0, 0);
    }
    float mA = -INFINITY, mB = -INFINITY;
#pragma unroll
    for (int reg = 0; reg < 8; ++reg) mA = fmaxf(mA, acc[reg]);
#pragma unroll
    for (int reg = 8; reg < 16; ++reg) mB = fmaxf(mB, acc[reg]);
    mA = fmaxf(mA, __shfl_xor(mA, 32, 64));
    mB = fmaxf(mB, __shfl_xor(mB, 32, 64));
    int col = w * 32 + q;
    int nodeA = n0 + rt * 2, nodeB = n0 + rt * 2 + 1;
    if (half == 0) {
      float v = mA + bias3;
      if (nadd) v += nadd[nodeA * 128 + col];
      eout[nodeA * 128 + col] = v;
    } else {
      float v = mB + bias3;
      if (nadd) v += nadd[nodeB * 128 + col];
      eout[nodeB * 128 + col] = v;
    }
  }
}

// ---------------- small epilogues ----------------
__global__ void k_e1n1(const float* __restrict__ e1, const float* __restrict__ n1,
                       float* s1) {
  int t = threadIdx.x;
  int node = blockIdx.x * 4 + (t >> 6);
  int lane = t & 63;
  float v0 = e1[node * 128 + lane] + n1[node * 128 + lane];
  float v1 = e1[node * 128 + 64 + lane] + n1[node * 128 + 64 + lane];
  float ss = v0 * v0 + v1 * v1;
#pragma unroll
  for (int off = 32; off; off >>= 1) ss += __shfl_down(ss, off, 64);
  if (lane == 0) s1[node] = sqrtf(ss);
}

__global__ void k_final(const float* __restrict__ s1, const float* __restrict__ e2n2,
                        const float* __restrict__ e3n3, float* __restrict__ out) {
  int t = threadIdx.x;
  int node = blockIdx.x * 4 + (t >> 6);
  int lane = t & 63;
  float s = s1[node];
  float z0 = s * e2n2[node * 128 + lane] * e3n3[node * 128 + lane];
  float z1 = s * e2n2[node * 128 + 64 + lane] * e3n3[node * 128 + 64 + lane];
  float m = fmaxf(z0, z1);
#pragma unroll
  for (int off = 32; off; off >>= 1) m = fmaxf(m, __shfl_xor(m, off, 64));
  float ex = expf(z0 - m) + expf(z1 - m);
#pragma unroll
  for (int off = 32; off; off >>= 1) ex += __shfl_xor(ex, off, 64);
  float lse = m + logf(ex);
  out[node * 128 + lane] = z0 - lse;
  out[node * 128 + 64 + lane] = z1 - lse;
}

// ---------------- host ----------------
extern "C" void kernel_launch(void* const* d_in, const int* in_sizes, int n_in,
                              void* d_out, int out_size, void* d_ws, size_t ws_size,
                              hipStream_t stream) {
  (void)in_sizes; (void)n_in; (void)out_size;
  const float* x  = (const float*)d_in[0];
  const int* ei   = (const int*)d_in[1];
  const float* ew = (const float*)d_in[2];
  const float* wg[3] = {(const float*)d_in[3], (const float*)d_in[5], (const float*)d_in[7]};
  const float* bg[3] = {(const float*)d_in[4], (const float*)d_in[6], (const float*)d_in[8]};
  const float* ew1[3] = {(const float*)d_in[9],  (const float*)d_in[15], (const float*)d_in[21]};
  const float* eb1[3] = {(const float*)d_in[10], (const float*)d_in[16], (const float*)d_in[22]};
  const float* ew2[3] = {(const float*)d_in[11], (const float*)d_in[17], (const float*)d_in[23]};
  const float* eb2[3] = {(const float*)d_in[12], (const float*)d_in[18], (const float*)d_in[24]};
  const float* ew3[3] = {(const float*)d_in[13], (const float*)d_in[19], (const float*)d_in[25]};
  const float* eb3[3] = {(const float*)d_in[14], (const float*)d_in[20], (const float*)d_in[26]};

  size_t small = (size_t)(23 * N_ + (N_ + 256) + N_ + 2 * E_);
  size_t need = (small + 172032 + (size_t)7 * N_ * H_) * sizeof(float);
  if (ws_size < need) return;

  float* ws  = (float*)d_ws;
  float* dis = ws;
  float* sn  = ws + N_;
  float* S1  = ws + 2 * N_;
  int* idx   = (int*)(ws + 3 * N_);
  int* cursor = (int*)(ws + 21 * N_);
  float* tauD = ws + 22 * N_;
  int* rowptr = (int*)(ws + 23 * N_);
  int* hist   = rowptr + N_ + 256;
  int* srcS   = hist + N_;
  float* normS = (float*)(srcS + E_);
  bshort8* wAll = (bshort8*)(normS + E_);     // 3 x 14336 bshort8
  float* h   = (float*)(normS + E_ + 172032);
  float* n1  = h + N_ * H_;
  float* n2  = n1 + N_ * H_;
  float* n3  = n2 + N_ * H_;
  float* E2  = n3 + N_ * H_;
  float* E1  = E2 + N_ * H_;
  float* ab  = E1 + N_ * H_;

  bshort8* fragHi = (bshort8*)h;
  bshort8* fragLo = (bshort8*)(h + N_ * H_ / 2);
  u64* candR  = (u64*)E1;                      // 128 rows over E1+ab (dead after tauseedX)
  u64* accept = (u64*)E1;                      // rows 0..127

  float* nl[3] = {n1, n2, n3};
  float* spare[3] = {n2, n1, n2};              // accExt rows 128..191, dead per layer
  float* nadd[3] = {nullptr, n2, n3};

  k_deg_init<<<N_ / 256, 256, 0, stream>>>(dis);
  k_deg_scatter<<<E_ / 256, 256, 0, stream>>>(ei, ew, dis);
  k_dis<<<N_ / 256, 256, 0, stream>>>(dis);
  hipMemsetAsync(hist, 0, N_ * sizeof(int), stream);
  k_hist<<<E_ / 256, 256, 0, stream>>>(ei, hist);
  k_scan<<<1, 256, 0, stream>>>(hist, rowptr);
  k_edgebuild<<<E_ / 256, 256, 0, stream>>>(ei, ew, dis, hist, srcS, normS);

  WP wp;
  for (int l = 0; l < 3; ++l) {
    wp.p[l * 4 + 0] = wg[l];
    wp.p[l * 4 + 1] = ew1[l];
    wp.p[l * 4 + 2] = ew2[l];
    wp.p[l * 4 + 3] = ew3[l];
  }
  k_wprepAll<<<84, 256, 0, stream>>>(wp, wAll);

  for (int l = 0; l < 3; ++l) {
    bshort8* wl = wAll + l * 14336;
    bshort8* wgfH = wl;            bshort8* wgfL = wl + 2048;
    bshort8* w1fH = wl + 4096;     bshort8* w1fL = wl + 6144;
    bshort8* w2fH = wl + 8192;     bshort8* w2fL = wl + 9216;
    bshort8* w3fH = wl + 10240;    bshort8* w3fL = wl + 12288;

    const float* inp = (l == 0) ? x : nl[l - 1];
    k_gemmM<<<256, 256, 0, stream>>>(inp, wgfH, wgfL, h);
    k_gcn_agg<<<N_ / 2, 256, 0, stream>>>(h, dis, rowptr, srcS, normS, bg[l], nl[l], sn);
    k_fragprep<<<N_ * 16 / 256, 256, 0, stream>>>(nl[l], fragHi, fragLo);
    k_knnA<<<dim3(N_ / 32, 4), 256, 0, stream>>>(fragHi, fragLo, sn, candR);
    k_tauseedX<<<N_ / 64, 256, 0, stream>>>(candR, cursor, tauD);
    k_knnB<<<dim3(N_ / 32, 8), 256, 0, stream>>>(fragHi, fragLo, sn, tauD, cursor,
                                                 accept, (u64*)spare[l]);
    k_select<<<N_ / 64, 256, 0, stream>>>(accept, (u64*)spare[l], cursor, idx);
    k_gemmMF<<<512, 128, 0, stream>>>(fragHi, fragLo, w1fH, w1fL, ab);
    float* etgt = (l == 1) ? E2 : E1;
    k_mlpM<<<N_ / 4, 256, 0, stream>>>(ab, idx, w2fH, w2fL, w3fH, w3fL,
                                       eb1[l], eb2[l], eb3[l], nadd[l], etgt);
    if (l == 0) k_e1n1<<<N_ / 4, 256, 0, stream>>>(E1, n1, S1);
  }
  k_final<<<N_ / 4, 256, 0, stream>>>(S1, E2, E1, (float*)d_out);
}